// Round 16
// baseline (112.050 us; speedup 1.0000x reference)
//
#include <hip/hip_runtime.h>
#include <hip/hip_bf16.h>
#include <math.h>

#define NNODES 131072
#define BN 64
#define TILES 2

typedef __attribute__((ext_vector_type(8))) short bf16x8;
typedef __attribute__((ext_vector_type(4))) float f32x4;

// bf16 weights (prep): W_h [128*64] @0 | W_s [128*256] @8192 | W_g [64*128] @40960
__device__ short g_w[49152];
// bf16 fused weight Wc[o][v] = sum_h W_V[o][h]*W_h[h][v], [64*64] row-major
__device__ short g_wc[4096];

__device__ __forceinline__ short f2b(float f) {
  union { float f; unsigned u; } x; x.f = f;
  unsigned r = x.u + 0x7fffu + ((x.u >> 16) & 1u);
  return (short)(r >> 16);
}
__device__ __forceinline__ short c2b(float f) {
  __hip_bfloat16 h = __float2bfloat16(f);
  return *reinterpret_cast<short*>(&h);
}

__global__ void prep_kernel(const float* __restrict__ W_h, const float* __restrict__ W_V,
                            const float* __restrict__ W_s_w, const float* __restrict__ W_g_w) {
  int b = blockIdx.x;
  if (b < 48) {
    int i4 = (b * 256 + threadIdx.x) * 4;
    const float* src;
    if (i4 < 8192)       src = W_h   + i4;
    else if (i4 < 40960) src = W_s_w + (i4 - 8192);
    else                 src = W_g_w + (i4 - 40960);
    float4 q = *(const float4*)src;
    short4 p;
    p.x = f2b(q.x); p.y = f2b(q.y); p.z = f2b(q.z); p.w = f2b(q.w);
    *(short4*)(g_w + i4) = p;
  } else {
    int gid = (b - 48) * 256 + threadIdx.x;   // 0..1023
    int o  = gid >> 4;
    int v0 = (gid & 15) * 4;
    float a0 = 0.f, a1 = 0.f, a2 = 0.f, a3 = 0.f;
    #pragma unroll 8
    for (int h = 0; h < 128; ++h) {
      float wv = W_V[o * 128 + h];
      float4 wh = *(const float4*)(W_h + h * 64 + v0);
      a0 += wv * wh.x; a1 += wv * wh.y; a2 += wv * wh.z; a3 += wv * wh.w;
    }
    short4 p;
    p.x = f2b(a0); p.y = f2b(a1); p.z = f2b(a2); p.w = f2b(a3);
    *(short4*)(g_wc + o * 64 + v0) = p;
  }
}

// R16 = R15 + persistent TILES=2 + register prefetch:
//   grid 1024 (2 tiles x 64 nodes per block) -> 2 generations/CU instead of 4;
//   tile-1 V/s prefetched into 40 regs AFTER tile-0's B1 (so B1's vmcnt(0)
//   drain does NOT wait on the prefetch); whole tile-0 chain hides the latency.
//   Reg budget: base 64 + 40 prefetch ~ 104 < 128 cap of (512,2) (R7 spilled at
//   ~160 under a 128 cap - that was the failure mode, not the idea).
//   Cost accepted: inter-tile B5 drains tile-0's just-issued global stores.
// LDS 57344 (2 blocks/CU), layout as R15:
//   Vt @0 (24576) | SCN @24576 (32768) | SOUT overlays SCN | VST @0 overlays all.
// Barriers/tile: B1 stage, B2 norm, B3, B3b, B4a, B4b (+B5 between tiles).

__global__ __launch_bounds__(512, 2)
void gvp_kernel(const float* __restrict__ s_in, const float* __restrict__ V_in,
                const float* __restrict__ W_s_b, const float* __restrict__ W_g_b,
                float* __restrict__ s_out_g, float* __restrict__ V_out_g)
{
  __shared__ __align__(16) char smem[57344];
  char*  const Vt   = smem;
  float* const VST  = (float*)smem;
  char*  const SCN  = smem + 24576;
  char*  const SOUT = smem + 24576;

  const short* const g_wh = g_w;
  const short* const g_ws = g_w + 8192;
  const short* const g_wg = g_w + 40960;

  const int t    = threadIdx.x;
  const int lane = t & 63;
  const int w    = t >> 6;          // 0..7
  const int w4   = w & 3;
  const int h2   = w >> 2;          // node-half for GEMM2/4
  const int l15  = lane & 15;
  const int lk8  = (lane >> 4) << 3;  // 0,8,16,24
  const int r4   = (lane >> 4) << 2;  // 0,4,8,12
  const long base = (long)blockIdx.x * (BN * TILES);

  const int snl = t >> 3;        // staging node 0..63
  const int svg = t & 7;
  const int sv0 = svg << 3;
  const int sk0 = svg << 4;

  // ---- preload tile 0 into registers ----
  float4 vr[6], sr[4];
  {
    const float* vp = V_in + (base + snl) * 192 + sv0 * 3;
    #pragma unroll
    for (int i = 0; i < 6; ++i) vr[i] = *(const float4*)(vp + 4 * i);
    const float* sp = s_in + (base + snl) * 128 + sk0;
    #pragma unroll
    for (int i = 0; i < 4; ++i) sr[i] = *(const float4*)(sp + 4 * i);
  }

  #pragma unroll
  for (int tt = 0; tt < TILES; ++tt) {
    const long n0 = base + (long)tt * BN;

    // ---- LDS stage: Vt from vr ----
    {
      float fl[24];
      #pragma unroll
      for (int i = 0; i < 6; ++i) *(float4*)(fl + 4 * i) = vr[i];
      #pragma unroll
      for (int c = 0; c < 3; ++c) {
        int row = (c << 6) + snl;
        bf16x8 p;
        #pragma unroll
        for (int j = 0; j < 8; ++j) p[j] = c2b(fl[j * 3 + c]);
        unsigned a = (unsigned)(row * 128) + (((unsigned)(sv0 * 2)) ^ (unsigned)((row & 7) << 4));
        *(bf16x8*)(Vt + a) = p;
      }
    }
    // ---- LDS stage: SCN cols 0-127 from sr ----
    {
      bf16x8 pa, pb;
      pa[0] = c2b(sr[0].x); pa[1] = c2b(sr[0].y); pa[2] = c2b(sr[0].z); pa[3] = c2b(sr[0].w);
      pa[4] = c2b(sr[1].x); pa[5] = c2b(sr[1].y); pa[6] = c2b(sr[1].z); pa[7] = c2b(sr[1].w);
      pb[0] = c2b(sr[2].x); pb[1] = c2b(sr[2].y); pb[2] = c2b(sr[2].z); pb[3] = c2b(sr[2].w);
      pb[4] = c2b(sr[3].x); pb[5] = c2b(sr[3].y); pb[6] = c2b(sr[3].z); pb[7] = c2b(sr[3].w);
      unsigned sw = (unsigned)((snl & 7) << 4);
      *(bf16x8*)(SCN + snl * 512 + (((unsigned)(sk0 * 2)) ^ sw))      = pa;
      *(bf16x8*)(SCN + snl * 512 + (((unsigned)(sk0 * 2 + 16)) ^ sw)) = pb;
    }
    __syncthreads();  // B1 (no prefetch outstanding here)

    // ---- prefetch NEXT tile AFTER B1: latency hides under the whole chain ----
    if (tt + 1 < TILES) {
      const float* vp = V_in + (n0 + BN + snl) * 192 + sv0 * 3;
      #pragma unroll
      for (int i = 0; i < 6; ++i) vr[i] = *(const float4*)(vp + 4 * i);
      const float* sp = s_in + (n0 + BN + snl) * 128 + sk0;
      #pragma unroll
      for (int i = 0; i < 4; ++i) sr[i] = *(const float4*)(sp + 4 * i);
    }

    // ---- hoisted weight fragments ----
    bf16x8 bf1[2];
    {
      int h = (w << 4) + l15;
      bf1[0] = *(const bf16x8*)(g_wh + h * 64 + lk8);
      bf1[1] = *(const bf16x8*)(g_wh + h * 64 + 32 + lk8);
    }
    bf16x8 b3[8];
    {
      int o = (w << 4) + l15;
      #pragma unroll
      for (int ks = 0; ks < 8; ++ks)
        b3[ks] = *(const bf16x8*)(g_ws + o * 256 + (ks << 5) + lk8);
    }
    bf16x8 bc[2];
    {
      int o = (w4 << 4) + l15;
      bc[0] = *(const bf16x8*)(g_wc + o * 64 + lk8);
      bc[1] = *(const bf16x8*)(g_wc + o * 64 + 32 + lk8);
    }

    // ---- GEMM1: Vh[c*64+nl][h], 192x128 K=64; wave w owns 16 h-cols ----
    f32x4 acc1[12];
    #pragma unroll
    for (int r = 0; r < 12; ++r) { f32x4 z = {0.f,0.f,0.f,0.f}; acc1[r] = z; }
    #pragma unroll
    for (int r = 0; r < 12; ++r) {
      int row = (r << 4) + l15;
      unsigned sw = (unsigned)((row & 7) << 4);
      bf16x8 af0 = *(const bf16x8*)(Vt + row * 128 + (((unsigned)(lk8 * 2)) ^ sw));
      bf16x8 af1 = *(const bf16x8*)(Vt + row * 128 + (((unsigned)((32 + lk8) * 2)) ^ sw));
      acc1[r] = __builtin_amdgcn_mfma_f32_16x16x32_bf16(af0, bf1[0], acc1[r], 0, 0, 0);
      acc1[r] = __builtin_amdgcn_mfma_f32_16x16x32_bf16(af1, bf1[1], acc1[r], 0, 0, 0);
    }

    // ---- Vh_norm -> SCN cols 128-255 ----
    {
      int col = 128 + (w << 4) + l15;
      #pragma unroll
      for (int q = 0; q < 4; ++q) {
        #pragma unroll
        for (int i = 0; i < 4; ++i) {
          int nl = (q << 4) + r4 + i;
          float x0 = acc1[q][i];
          float x1 = acc1[4 + q][i];
          float x2 = acc1[8 + q][i];
          float nrm = sqrtf(x0 * x0 + x1 * x1 + x2 * x2);
          unsigned a = (unsigned)(nl * 512) + (((unsigned)(col * 2)) ^ (unsigned)((nl & 7) << 4));
          *(short*)(SCN + a) = c2b(nrm);
        }
      }
    }
    __syncthreads();  // B2 (acc1 dead)

    // ---- hoist GEMM4 weights under GEMM3 ----
    bf16x8 b4[4];
    {
      int o = (w4 << 4) + l15;
      #pragma unroll
      for (int ks = 0; ks < 4; ++ks)
        b4[ks] = *(const bf16x8*)(g_wg + o * 128 + (ks << 5) + lk8);
    }

    // ---- GEMM3: s_out 64x128 K=256; wave w owns 16 cols; 32 MFMA ----
    f32x4 acc3[4];
    #pragma unroll
    for (int rt = 0; rt < 4; ++rt) { f32x4 z = {0.f,0.f,0.f,0.f}; acc3[rt] = z; }
    #pragma unroll
    for (int ks = 0; ks < 8; ++ks) {
      #pragma unroll
      for (int rt = 0; rt < 4; ++rt) {
        int row = (rt << 4) + l15;
        unsigned sw = (unsigned)((row & 7) << 4);
        bf16x8 a = *(const bf16x8*)(SCN + row * 512 +
                     (((unsigned)(((ks << 5) + lk8) * 2)) ^ sw));
        acc3[rt] = __builtin_amdgcn_mfma_f32_16x16x32_bf16(a, b3[ks], acc3[rt], 0, 0, 0);
      }
    }

    // ---- GEMM2 (fused Wc): cols w4, node-half h2 ----
    f32x4 acc2[3][2];
    #pragma unroll
    for (int c = 0; c < 3; ++c)
      #pragma unroll
      for (int j = 0; j < 2; ++j) { f32x4 z = {0.f,0.f,0.f,0.f}; acc2[c][j] = z; }
    #pragma unroll
    for (int c = 0; c < 3; ++c) {
      #pragma unroll
      for (int j = 0; j < 2; ++j) {
        int r = c * 4 + 2 * h2 + j;
        int row = (r << 4) + l15;
        unsigned sw = (unsigned)((row & 7) << 4);
        bf16x8 af0 = *(const bf16x8*)(Vt + row * 128 + (((unsigned)(lk8 * 2)) ^ sw));
        bf16x8 af1 = *(const bf16x8*)(Vt + row * 128 + (((unsigned)((32 + lk8) * 2)) ^ sw));
        acc2[c][j] = __builtin_amdgcn_mfma_f32_16x16x32_bf16(af0, bc[0], acc2[c][j], 0, 0, 0);
        acc2[c][j] = __builtin_amdgcn_mfma_f32_16x16x32_bf16(af1, bc[1], acc2[c][j], 0, 0, 0);
      }
    }

    // ---- s_out values -> regs (stores deferred) ----
    float so[4][4];
    {
      float bias = W_s_b[(w << 4) + l15];
      #pragma unroll
      for (int rt = 0; rt < 4; ++rt)
        #pragma unroll
        for (int i = 0; i < 4; ++i)
          so[rt][i] = fmaxf(acc3[rt][i] + bias, 0.0f);
    }
    __syncthreads();  // B3: SCN reads (GEMM3) + Vt reads (GEMM2) done

    // ---- SOUT stage (overlays SCN) ----
    {
      int col = (w << 4) + l15;
      #pragma unroll
      for (int rt = 0; rt < 4; ++rt) {
        #pragma unroll
        for (int i = 0; i < 4; ++i) {
          int row = (rt << 4) + r4 + i;
          unsigned a = (unsigned)(row * 256) + (((unsigned)(col * 2)) ^ (unsigned)((row & 7) << 4));
          *(short*)(SOUT + a) = c2b(so[rt][i]);
        }
      }
    }
    __syncthreads();  // B3b: SOUT visible

    // ---- GEMM4: gate logits; cols w4, rows rt = 2*h2+j ----
    f32x4 acc4[2];
    { f32x4 z = {0.f,0.f,0.f,0.f}; acc4[0] = z; acc4[1] = z; }
    #pragma unroll
    for (int ks = 0; ks < 4; ++ks) {
      #pragma unroll
      for (int j = 0; j < 2; ++j) {
        int row = ((2 * h2 + j) << 4) + l15;
        bf16x8 a = *(const bf16x8*)(SOUT + row * 256 +
                     (((unsigned)(((ks << 5) + lk8) * 2)) ^ ((unsigned)((row & 7) << 4))));
        acc4[j] = __builtin_amdgcn_mfma_f32_16x16x32_bf16(a, b4[ks], acc4[j], 0, 0, 0);
      }
    }
    float sg[2][4];
    {
      float biasg = W_g_b[(w4 << 4) + l15];
      #pragma unroll
      for (int j = 0; j < 2; ++j)
        #pragma unroll
        for (int i = 0; i < 4; ++i)
          sg[j][i] = 1.0f / (1.0f + __expf(-(acc4[j][i] + biasg)));
    }
    __syncthreads();  // B4a: SOUT reads done -> VST overlay allowed

    // ---- gate apply -> VST [64][768B] f32 swz ----
    {
      int col = (w4 << 4) + l15;
      #pragma unroll
      for (int c = 0; c < 3; ++c) {
        #pragma unroll
        for (int j = 0; j < 2; ++j) {
          #pragma unroll
          for (int i = 0; i < 4; ++i) {
            int nl = ((2 * h2 + j) << 4) + r4 + i;
            unsigned a = (unsigned)(nl * 768) +
                         (((unsigned)((col * 3 + c) * 4)) ^ (unsigned)((nl & 7) << 4));
            *(float*)((char*)VST + a) = acc2[c][j][i] * sg[j][i];
          }
        }
      }
    }
    __syncthreads();  // B4b: VST visible

    // ---- global stores (after last barrier of this tile) ----
    {
      float4* Vo = (float4*)(V_out_g + n0 * 192);
      #pragma unroll
      for (int m = 0; m < 6; ++m) {
        int f = m * 512 + t;                 // 0..3071 flat float4 idx
        int nl = f / 48;
        int rem = f - nl * 48;
        float4 q = *(const float4*)((char*)VST + nl * 768 +
                     (((unsigned)(rem * 16)) ^ ((unsigned)((nl & 7) << 4))));
        Vo[f] = q;
      }
    }
    {
      int col = (w << 4) + l15;
      #pragma unroll
      for (int rt = 0; rt < 4; ++rt) {
        #pragma unroll
        for (int i = 0; i < 4; ++i) {
          int nl = (rt << 4) + r4 + i;
          s_out_g[(n0 + nl) * 128 + col] = so[rt][i];
        }
      }
    }
    if (tt + 1 < TILES) __syncthreads();  // B5: VST reads done before next stage
  }
}

extern "C" void kernel_launch(void* const* d_in, const int* in_sizes, int n_in,
                              void* d_out, int out_size, void* d_ws, size_t ws_size,
                              hipStream_t stream) {
  const float* s_in  = (const float*)d_in[0];
  const float* V_in  = (const float*)d_in[1];
  const float* W_h   = (const float*)d_in[2];
  const float* W_V   = (const float*)d_in[3];
  const float* W_s_w = (const float*)d_in[4];
  const float* W_s_b = (const float*)d_in[5];
  const float* W_g_w = (const float*)d_in[6];
  const float* W_g_b = (const float*)d_in[7];
  float* out = (float*)d_out;
  float* s_out_g = out;
  float* V_out_g = out + (size_t)NNODES * 128;
  hipLaunchKernelGGL(prep_kernel, dim3(52), dim3(256), 0, stream,
                     W_h, W_V, W_s_w, W_g_w);
  hipLaunchKernelGGL(gvp_kernel, dim3(NNODES / (BN * TILES)), dim3(512), 0, stream,
                     s_in, V_in, W_s_b, W_g_b, s_out_g, V_out_g);
}

// Round 17
// 94.202 us; speedup vs baseline: 1.1895x; 1.1895x over previous
//
#include <hip/hip_runtime.h>
#include <hip/hip_bf16.h>
#include <math.h>

#define NNODES 131072
#define BN 64

typedef __attribute__((ext_vector_type(8))) short bf16x8;
typedef __attribute__((ext_vector_type(4))) float f32x4;

// bf16 weights (prep): W_h [128*64] @0 | W_s [128*256] @8192 | W_g [64*128] @40960
__device__ short g_w[49152];
// bf16 fused weight Wc[o][v] = sum_h W_V[o][h]*W_h[h][v], [64*64] row-major
__device__ short g_wc[4096];

__device__ __forceinline__ short f2b(float f) {
  union { float f; unsigned u; } x; x.f = f;
  unsigned r = x.u + 0x7fffu + ((x.u >> 16) & 1u);
  return (short)(r >> 16);
}
__device__ __forceinline__ short c2b(float f) {
  __hip_bfloat16 h = __float2bfloat16(f);
  return *reinterpret_cast<short*>(&h);
}

__global__ void prep_kernel(const float* __restrict__ W_h, const float* __restrict__ W_V,
                            const float* __restrict__ W_s_w, const float* __restrict__ W_g_w) {
  int b = blockIdx.x;
  if (b < 48) {
    int i4 = (b * 256 + threadIdx.x) * 4;
    const float* src;
    if (i4 < 8192)       src = W_h   + i4;
    else if (i4 < 40960) src = W_s_w + (i4 - 8192);
    else                 src = W_g_w + (i4 - 40960);
    float4 q = *(const float4*)src;
    short4 p;
    p.x = f2b(q.x); p.y = f2b(q.y); p.z = f2b(q.z); p.w = f2b(q.w);
    *(short4*)(g_w + i4) = p;
  } else {
    int gid = (b - 48) * 256 + threadIdx.x;   // 0..1023
    int o  = gid >> 4;
    int v0 = (gid & 15) * 4;
    float a0 = 0.f, a1 = 0.f, a2 = 0.f, a3 = 0.f;
    #pragma unroll 8
    for (int h = 0; h < 128; ++h) {
      float wv = W_V[o * 128 + h];
      float4 wh = *(const float4*)(W_h + h * 64 + v0);
      a0 += wv * wh.x; a1 += wv * wh.y; a2 += wv * wh.z; a3 += wv * wh.w;
    }
    short4 p;
    p.x = f2b(a0); p.y = f2b(a1); p.z = f2b(a2); p.w = f2b(a3);
    *(short4*)(g_wc + o * 64 + v0) = p;
  }
}

// R17 = R15 verbatim (best measured: 95.6 us). R16's persistence variant
// regressed (occupancy 38->21%, B5 store-drain serialization) and is reverted.
// LDS 57344 (2 blocks/CU):
//   Vt   @0     (24576): [192 rows = c*64+nl][128B] bf16 swz
//   SCN  @24576 (32768): [64][512B] bf16 swz (s cols 0-127, norm 128-255)
//   SOUT @24576 (16384): [64][256B] bf16 swz  (overlays SCN after B3)
//   VST  @0     (49152): [64][768B] f32 swz   (overlays all after B4a)
// Wave split: GEMM1/GEMM3 col group w (16 cols of 128);
//   GEMM2/GEMM4 col group w&3 (16 of 64) x node-half h2=w>>2 (nl 0-31 / 32-63).
// Barriers: B1 stage, B2 norm, B3 SCN/Vt reads done, B3b SOUT, B4a SOUT reads
//   done, B4b VST visible. No global store pending at any barrier.

__global__ __launch_bounds__(512, 2)
void gvp_kernel(const float* __restrict__ s_in, const float* __restrict__ V_in,
                const float* __restrict__ W_s_b, const float* __restrict__ W_g_b,
                float* __restrict__ s_out_g, float* __restrict__ V_out_g)
{
  __shared__ __align__(16) char smem[57344];
  char*  const Vt   = smem;
  float* const VST  = (float*)smem;
  char*  const SCN  = smem + 24576;
  char*  const SOUT = smem + 24576;

  const short* const g_wh = g_w;
  const short* const g_ws = g_w + 8192;
  const short* const g_wg = g_w + 40960;

  const int t    = threadIdx.x;
  const int lane = t & 63;
  const int w    = t >> 6;          // 0..7
  const int w4   = w & 3;
  const int h2   = w >> 2;          // node-half for GEMM2/4
  const int l15  = lane & 15;
  const int lk8  = (lane >> 4) << 3;  // 0,8,16,24
  const int r4   = (lane >> 4) << 2;  // 0,4,8,12
  const long n0  = (long)blockIdx.x * BN;

  // ---- stage V tile: thread (nl, vg) loads 24 contiguous floats of node nl ----
  {
    const int nl = t >> 3;        // 0..63
    const int vg = t & 7;
    const int v0 = vg << 3;
    const float* vp = V_in + (n0 + nl) * 192 + v0 * 3;   // 96B contiguous
    float fl[24];
    #pragma unroll
    for (int i = 0; i < 6; ++i) *(float4*)(fl + 4 * i) = *(const float4*)(vp + 4 * i);
    #pragma unroll
    for (int c = 0; c < 3; ++c) {
      int row = (c << 6) + nl;
      bf16x8 p;
      #pragma unroll
      for (int j = 0; j < 8; ++j) p[j] = c2b(fl[j * 3 + c]);
      unsigned a = (unsigned)(row * 128) + (((unsigned)(v0 * 2)) ^ (unsigned)((row & 7) << 4));
      *(bf16x8*)(Vt + a) = p;
    }
  }
  // ---- stage s tile -> SCN cols 0-127 ----
  {
    const int nl = t >> 3;
    const int kg = t & 7;
    const int k0 = kg << 4;
    const float* sp = s_in + (n0 + nl) * 128 + k0;       // 64B contiguous
    float4 q0 = *(const float4*)(sp);
    float4 q1 = *(const float4*)(sp + 4);
    float4 q2 = *(const float4*)(sp + 8);
    float4 q3 = *(const float4*)(sp + 12);
    bf16x8 pa, pb;
    pa[0] = c2b(q0.x); pa[1] = c2b(q0.y); pa[2] = c2b(q0.z); pa[3] = c2b(q0.w);
    pa[4] = c2b(q1.x); pa[5] = c2b(q1.y); pa[6] = c2b(q1.z); pa[7] = c2b(q1.w);
    pb[0] = c2b(q2.x); pb[1] = c2b(q2.y); pb[2] = c2b(q2.z); pb[3] = c2b(q2.w);
    pb[4] = c2b(q3.x); pb[5] = c2b(q3.y); pb[6] = c2b(q3.z); pb[7] = c2b(q3.w);
    unsigned sw = (unsigned)((nl & 7) << 4);
    *(bf16x8*)(SCN + nl * 512 + (((unsigned)(k0 * 2)) ^ sw))      = pa;
    *(bf16x8*)(SCN + nl * 512 + (((unsigned)(k0 * 2 + 16)) ^ sw)) = pb;
  }
  __syncthreads();  // B1

  // ---- hoisted weight fragments ----
  bf16x8 bf1[2];
  {
    int h = (w << 4) + l15;
    bf1[0] = *(const bf16x8*)(g_wh + h * 64 + lk8);
    bf1[1] = *(const bf16x8*)(g_wh + h * 64 + 32 + lk8);
  }
  bf16x8 b3[8];
  {
    int o = (w << 4) + l15;
    #pragma unroll
    for (int ks = 0; ks < 8; ++ks)
      b3[ks] = *(const bf16x8*)(g_ws + o * 256 + (ks << 5) + lk8);
  }
  bf16x8 bc[2];
  {
    int o = (w4 << 4) + l15;
    bc[0] = *(const bf16x8*)(g_wc + o * 64 + lk8);
    bc[1] = *(const bf16x8*)(g_wc + o * 64 + 32 + lk8);
  }

  // ---- GEMM1: Vh[c*64+nl][h], 192x128 K=64; wave w owns 16 h-cols ----
  f32x4 acc1[12];
  #pragma unroll
  for (int r = 0; r < 12; ++r) { f32x4 z = {0.f,0.f,0.f,0.f}; acc1[r] = z; }
  #pragma unroll
  for (int r = 0; r < 12; ++r) {
    int row = (r << 4) + l15;
    unsigned sw = (unsigned)((row & 7) << 4);
    bf16x8 af0 = *(const bf16x8*)(Vt + row * 128 + (((unsigned)(lk8 * 2)) ^ sw));
    bf16x8 af1 = *(const bf16x8*)(Vt + row * 128 + (((unsigned)((32 + lk8) * 2)) ^ sw));
    acc1[r] = __builtin_amdgcn_mfma_f32_16x16x32_bf16(af0, bf1[0], acc1[r], 0, 0, 0);
    acc1[r] = __builtin_amdgcn_mfma_f32_16x16x32_bf16(af1, bf1[1], acc1[r], 0, 0, 0);
  }

  // ---- Vh_norm -> SCN cols 128-255 (combine c-groups r = c*4+q) ----
  {
    int col = 128 + (w << 4) + l15;
    #pragma unroll
    for (int q = 0; q < 4; ++q) {
      #pragma unroll
      for (int i = 0; i < 4; ++i) {
        int nl = (q << 4) + r4 + i;
        float x0 = acc1[q][i];
        float x1 = acc1[4 + q][i];
        float x2 = acc1[8 + q][i];
        float nrm = sqrtf(x0 * x0 + x1 * x1 + x2 * x2);
        unsigned a = (unsigned)(nl * 512) + (((unsigned)(col * 2)) ^ (unsigned)((nl & 7) << 4));
        *(short*)(SCN + a) = c2b(nrm);
      }
    }
  }
  __syncthreads();  // B2 (acc1 dead)

  // ---- hoist GEMM4 weights under GEMM3 ----
  bf16x8 b4[4];
  {
    int o = (w4 << 4) + l15;
    #pragma unroll
    for (int ks = 0; ks < 4; ++ks)
      b4[ks] = *(const bf16x8*)(g_wg + o * 128 + (ks << 5) + lk8);
  }

  // ---- GEMM3: s_out 64x128 K=256; wave w owns 16 cols; 32 MFMA ----
  f32x4 acc3[4];
  #pragma unroll
  for (int rt = 0; rt < 4; ++rt) { f32x4 z = {0.f,0.f,0.f,0.f}; acc3[rt] = z; }
  #pragma unroll
  for (int ks = 0; ks < 8; ++ks) {
    #pragma unroll
    for (int rt = 0; rt < 4; ++rt) {
      int row = (rt << 4) + l15;
      unsigned sw = (unsigned)((row & 7) << 4);
      bf16x8 a = *(const bf16x8*)(SCN + row * 512 +
                   (((unsigned)(((ks << 5) + lk8) * 2)) ^ sw));
      acc3[rt] = __builtin_amdgcn_mfma_f32_16x16x32_bf16(a, b3[ks], acc3[rt], 0, 0, 0);
    }
  }

  // ---- GEMM2 (fused Wc): cols w4, node-half h2; rows r = c*4 + (2*h2+j) ----
  f32x4 acc2[3][2];
  #pragma unroll
  for (int c = 0; c < 3; ++c)
    #pragma unroll
    for (int j = 0; j < 2; ++j) { f32x4 z = {0.f,0.f,0.f,0.f}; acc2[c][j] = z; }
  #pragma unroll
  for (int c = 0; c < 3; ++c) {
    #pragma unroll
    for (int j = 0; j < 2; ++j) {
      int r = c * 4 + 2 * h2 + j;
      int row = (r << 4) + l15;
      unsigned sw = (unsigned)((row & 7) << 4);
      bf16x8 af0 = *(const bf16x8*)(Vt + row * 128 + (((unsigned)(lk8 * 2)) ^ sw));
      bf16x8 af1 = *(const bf16x8*)(Vt + row * 128 + (((unsigned)((32 + lk8) * 2)) ^ sw));
      acc2[c][j] = __builtin_amdgcn_mfma_f32_16x16x32_bf16(af0, bc[0], acc2[c][j], 0, 0, 0);
      acc2[c][j] = __builtin_amdgcn_mfma_f32_16x16x32_bf16(af1, bc[1], acc2[c][j], 0, 0, 0);
    }
  }

  // ---- s_out values -> regs (stores deferred to kernel end) ----
  float so[4][4];
  {
    float bias = W_s_b[(w << 4) + l15];
    #pragma unroll
    for (int rt = 0; rt < 4; ++rt)
      #pragma unroll
      for (int i = 0; i < 4; ++i)
        so[rt][i] = fmaxf(acc3[rt][i] + bias, 0.0f);
  }
  __syncthreads();  // B3: SCN reads (GEMM3) + Vt reads (GEMM2) done

  // ---- SOUT stage (overlays SCN) ----
  {
    int col = (w << 4) + l15;
    #pragma unroll
    for (int rt = 0; rt < 4; ++rt) {
      #pragma unroll
      for (int i = 0; i < 4; ++i) {
        int row = (rt << 4) + r4 + i;
        unsigned a = (unsigned)(row * 256) + (((unsigned)(col * 2)) ^ (unsigned)((row & 7) << 4));
        *(short*)(SOUT + a) = c2b(so[rt][i]);
      }
    }
  }
  __syncthreads();  // B3b: SOUT visible

  // ---- GEMM4: gate logits; cols w4, rows rt = 2*h2+j ----
  f32x4 acc4[2];
  { f32x4 z = {0.f,0.f,0.f,0.f}; acc4[0] = z; acc4[1] = z; }
  #pragma unroll
  for (int ks = 0; ks < 4; ++ks) {
    #pragma unroll
    for (int j = 0; j < 2; ++j) {
      int row = ((2 * h2 + j) << 4) + l15;
      bf16x8 a = *(const bf16x8*)(SOUT + row * 256 +
                   (((unsigned)(((ks << 5) + lk8) * 2)) ^ ((unsigned)((row & 7) << 4))));
      acc4[j] = __builtin_amdgcn_mfma_f32_16x16x32_bf16(a, b4[ks], acc4[j], 0, 0, 0);
    }
  }
  float sg[2][4];
  {
    float biasg = W_g_b[(w4 << 4) + l15];
    #pragma unroll
    for (int j = 0; j < 2; ++j)
      #pragma unroll
      for (int i = 0; i < 4; ++i)
        sg[j][i] = 1.0f / (1.0f + __expf(-(acc4[j][i] + biasg)));
  }
  __syncthreads();  // B4a: SOUT reads done -> VST overlay allowed

  // ---- gate apply -> VST [64][768B] f32 swz (single write phase) ----
  {
    int col = (w4 << 4) + l15;
    #pragma unroll
    for (int c = 0; c < 3; ++c) {
      #pragma unroll
      for (int j = 0; j < 2; ++j) {
        #pragma unroll
        for (int i = 0; i < 4; ++i) {
          int nl = ((2 * h2 + j) << 4) + r4 + i;
          unsigned a = (unsigned)(nl * 768) +
                       (((unsigned)((col * 3 + c) * 4)) ^ (unsigned)((nl & 7) << 4));
          *(float*)((char*)VST + a) = acc2[c][j][i] * sg[j][i];
        }
      }
    }
  }
  __syncthreads();  // B4b: VST visible

  // ---- all global stores AFTER the last barrier ----
  {
    float4* Vo = (float4*)(V_out_g + n0 * 192);
    #pragma unroll
    for (int m = 0; m < 6; ++m) {
      int f = m * 512 + t;                 // 0..3071 flat float4 idx
      int nl = f / 48;
      int rem = f - nl * 48;
      float4 q = *(const float4*)((char*)VST + nl * 768 +
                   (((unsigned)(rem * 16)) ^ ((unsigned)((nl & 7) << 4))));
      Vo[f] = q;
    }
  }
  {
    int col = (w << 4) + l15;
    #pragma unroll
    for (int rt = 0; rt < 4; ++rt) {
      #pragma unroll
      for (int i = 0; i < 4; ++i) {
        int nl = (rt << 4) + r4 + i;
        s_out_g[(n0 + nl) * 128 + col] = so[rt][i];
      }
    }
  }
}

extern "C" void kernel_launch(void* const* d_in, const int* in_sizes, int n_in,
                              void* d_out, int out_size, void* d_ws, size_t ws_size,
                              hipStream_t stream) {
  const float* s_in  = (const float*)d_in[0];
  const float* V_in  = (const float*)d_in[1];
  const float* W_h   = (const float*)d_in[2];
  const float* W_V   = (const float*)d_in[3];
  const float* W_s_w = (const float*)d_in[4];
  const float* W_s_b = (const float*)d_in[5];
  const float* W_g_w = (const float*)d_in[6];
  const float* W_g_b = (const float*)d_in[7];
  float* out = (float*)d_out;
  float* s_out_g = out;
  float* V_out_g = out + (size_t)NNODES * 128;
  hipLaunchKernelGGL(prep_kernel, dim3(52), dim3(256), 0, stream,
                     W_h, W_V, W_s_w, W_g_w);
  hipLaunchKernelGGL(gvp_kernel, dim3(NNODES / BN), dim3(512), 0, stream,
                     s_in, V_in, W_s_b, W_g_b, s_out_g, V_out_g);
}